// Round 1
// baseline (185.280 us; speedup 1.0000x reference)
//
#include <hip/hip_runtime.h>

// Neighbor-list (TorchNeighborList) for MI355X.
// Output layout (floats): [idx_i (M)] [idx_j (M)] [offset (M*3)] [valid (M)]
// where M = 2P rows, P = N(N-1)/2 + S*N*N.
// Valid rows are grouped by atom i ascending; within group: forward entries
// (i as pi: triu j>i, then (s,j) lexicographic) then backward entries
// (i as pj: triu a<i, then (s,a) lexicographic) — exactly reproducing the
// reference's stable argsort order. Invalid tail = (-1,-1,0,0,0,0).

#define WAVE 64
#define MAX_SHIFTS 64

__device__ __forceinline__ bool pair_valid(const float* __restrict__ pos,
                                           int pi, int pj,
                                           float sx, float sy, float sz,
                                           float cutoff) {
#pragma clang fp contract(off)
  float dx = pos[pi * 3 + 0] - pos[pj * 3 + 0] + sx;
  float dy = pos[pi * 3 + 1] - pos[pj * 3 + 1] + sy;
  float dz = pos[pi * 3 + 2] - pos[pj * 3 + 2] + sz;
  float d2 = dx * dx + dy * dy + dz * dz;   // contract(off): (x2+y2)+z2, numpy order
  return sqrtf(d2) < cutoff;
}

__global__ void k_fill(float4* __restrict__ out, long n4, long neg4,
                       float* __restrict__ outf, long ntail_lo, long ntail_hi) {
  long i = (long)blockIdx.x * blockDim.x + threadIdx.x;
  long stride = (long)gridDim.x * blockDim.x;
  const float4 neg = make_float4(-1.f, -1.f, -1.f, -1.f);
  const float4 zer = make_float4(0.f, 0.f, 0.f, 0.f);
  for (long k = i; k < n4; k += stride) out[k] = (k < neg4) ? neg : zer;
  // scalar tail (out_size not divisible by 4 — defensive, normally empty)
  for (long k = ntail_lo + i; k < ntail_hi; k += stride) outf[k] = 0.f;
}

__device__ __forceinline__ void load_shift_vecs(const float* __restrict__ box,
                                                const int* __restrict__ shifts,
                                                int S, float* sv, int tid,
                                                int nthreads) {
#pragma clang fp contract(off)
  for (int s = tid; s < S; s += nthreads) {
    float s0 = (float)shifts[s * 3 + 0];
    float s1 = (float)shifts[s * 3 + 1];
    float s2 = (float)shifts[s * 3 + 2];
    sv[s * 3 + 0] = s0 * box[0] + s1 * box[3] + s2 * box[6];
    sv[s * 3 + 1] = s0 * box[1] + s1 * box[4] + s2 * box[7];
    sv[s * 3 + 2] = s0 * box[2] + s1 * box[5] + s2 * box[8];
  }
}

__global__ void k_count(const float* __restrict__ pos, const float* __restrict__ box,
                        const int* __restrict__ shifts, const float* __restrict__ cutp,
                        int N, int S, int* __restrict__ count) {
  __shared__ float sv[MAX_SHIFTS * 3];
  __shared__ int rf[4], rb[4];
  int atom = blockIdx.x;
  int t = threadIdx.x;
  float cutoff = cutp[0];
  load_shift_vecs(box, shifts, S, sv, t, blockDim.x);
  __syncthreads();

  int cnt_f = 0, cnt_b = 0;
  {  // forward: pi = atom
    int ntriu = N - 1 - atom;
    int ncand = ntriu + S * N;
    for (int c = t; c < ncand; c += blockDim.x) {
      int j;
      float sx = 0.f, sy = 0.f, sz = 0.f;
      if (c < ntriu) {
        j = atom + 1 + c;
      } else {
        int cc = c - ntriu;
        int s = cc / N;
        j = cc - s * N;
        sx = sv[s * 3 + 0]; sy = sv[s * 3 + 1]; sz = sv[s * 3 + 2];
      }
      if (pair_valid(pos, atom, j, sx, sy, sz, cutoff)) cnt_f++;
    }
  }
  {  // backward: pj = atom
    int ntriu = atom;
    int ncand = ntriu + S * N;
    for (int c = t; c < ncand; c += blockDim.x) {
      int a;
      float sx = 0.f, sy = 0.f, sz = 0.f;
      if (c < ntriu) {
        a = c;
      } else {
        int cc = c - ntriu;
        int s = cc / N;
        a = cc - s * N;
        sx = sv[s * 3 + 0]; sy = sv[s * 3 + 1]; sz = sv[s * 3 + 2];
      }
      if (pair_valid(pos, a, atom, sx, sy, sz, cutoff)) cnt_b++;
    }
  }
  for (int off = 32; off; off >>= 1) {
    cnt_f += __shfl_down(cnt_f, off);
    cnt_b += __shfl_down(cnt_b, off);
  }
  int wid = t >> 6;
  if ((t & 63) == 0) { rf[wid] = cnt_f; rb[wid] = cnt_b; }
  __syncthreads();
  if (t == 0) {
    int nw = blockDim.x >> 6;
    int f = 0, b = 0;
    for (int w = 0; w < nw; w++) { f += rf[w]; b += rb[w]; }
    count[2 * atom + 0] = f;
    count[2 * atom + 1] = b;
  }
}

__global__ void k_scan(const int* __restrict__ count, int* __restrict__ start, int n) {
  int lane = threadIdx.x;  // 64 threads
  int chunk = (n + 63) >> 6;
  int lo = lane * chunk;
  int hi = min(lo + chunk, n);
  int sum = 0;
  for (int i = lo; i < hi; i++) sum += count[i];
  int incl = sum;
  for (int off = 1; off < 64; off <<= 1) {
    int v = __shfl_up(incl, off);
    if (lane >= off) incl += v;
  }
  int run = incl - sum;  // exclusive
  for (int i = lo; i < hi; i++) { start[i] = run; run += count[i]; }
}

__global__ void k_write(const float* __restrict__ pos, const float* __restrict__ box,
                        const int* __restrict__ shifts, const float* __restrict__ cutp,
                        int N, int S, const int* __restrict__ start,
                        float* __restrict__ out, long M) {
  __shared__ float sv[MAX_SHIFTS * 3];
  int g = blockIdx.x;
  int atom = g >> 1;
  int dir = g & 1;  // 0 = forward (atom is pi), 1 = backward (atom is pj)
  int lane = threadIdx.x;  // 64 = one wave
  float cutoff = cutp[0];
  load_shift_vecs(box, shifts, S, sv, lane, 64);
  __syncthreads();

  float* __restrict__ out_i = out;
  float* __restrict__ out_j = out + M;
  float* __restrict__ out_off = out + 2 * M;
  float* __restrict__ out_v = out + 5 * M;

  int ntriu = (dir == 0) ? (N - 1 - atom) : atom;
  int ncand = ntriu + S * N;
  long base = start[g];
  int running = 0;
  float fatom = (float)atom;

  for (int c0 = 0; c0 < ncand; c0 += WAVE) {
    int c = c0 + lane;
    bool v = false;
    int other = 0;
    float ox = 0.f, oy = 0.f, oz = 0.f;
    if (c < ncand) {
      float sx = 0.f, sy = 0.f, sz = 0.f;
      if (c < ntriu) {
        other = (dir == 0) ? (atom + 1 + c) : c;
      } else {
        int cc = c - ntriu;
        int s = cc / N;
        other = cc - s * N;
        sx = sv[s * 3 + 0]; sy = sv[s * 3 + 1]; sz = sv[s * 3 + 2];
      }
      int pi = (dir == 0) ? atom : other;
      int pj = (dir == 0) ? other : atom;
      v = pair_valid(pos, pi, pj, sx, sy, sz, cutoff);
      // output offset: first half gets -shift, second half +shift (ref bi_off)
      if (dir == 0) { ox = -sx; oy = -sy; oz = -sz; }
      else          { ox =  sx; oy =  sy; oz =  sz; }
    }
    unsigned long long m = __ballot(v);
    if (v) {
      int rank = __popcll(m & ((1ULL << lane) - 1ULL));
      long row = base + running + rank;
      out_i[row] = fatom;
      out_j[row] = (float)other;
      out_off[row * 3 + 0] = ox;
      out_off[row * 3 + 1] = oy;
      out_off[row * 3 + 2] = oz;
      out_v[row] = 1.0f;
    }
    running += __popcll(m);
  }
}

extern "C" void kernel_launch(void* const* d_in, const int* in_sizes, int n_in,
                              void* d_out, int out_size, void* d_ws, size_t ws_size,
                              hipStream_t stream) {
  const float* pos = (const float*)d_in[0];
  const float* box = (const float*)d_in[1];
  const int* shifts = (const int*)d_in[2];
  const float* cutp = (const float*)d_in[3];
  int N = in_sizes[0] / 3;
  int S = in_sizes[2] / 3;
  long M = (long)out_size / 6;  // number of output rows = 2P
  float* out = (float*)d_out;

  int* count = (int*)d_ws;
  int* start = count + 2 * N;

  long n4 = (long)out_size / 4;
  long neg4 = (2 * M) / 4;  // idx_i + idx_j regions, in float4 units
  long tail_lo = n4 * 4, tail_hi = (long)out_size;

  hipLaunchKernelGGL(k_fill, dim3(2048), dim3(256), 0, stream,
                     (float4*)out, n4, neg4, out, tail_lo, tail_hi);
  hipLaunchKernelGGL(k_count, dim3(N), dim3(256), 0, stream,
                     pos, box, shifts, cutp, N, S, count);
  hipLaunchKernelGGL(k_scan, dim3(1), dim3(64), 0, stream, count, start, 2 * N);
  hipLaunchKernelGGL(k_write, dim3(2 * N), dim3(64), 0, stream,
                     pos, box, shifts, cutp, N, S, start, out, M);
}

// Round 3
// 134.798 us; speedup vs baseline: 1.3745x; 1.3745x over previous
//
#include <hip/hip_runtime.h>

#pragma clang fp contract(off)

// Neighbor-list (TorchNeighborList) for MI355X.
// Output layout (floats): [idx_i (M)] [idx_j (M)] [offset (M*3)] [valid (M)]
// where M = 2P rows, P = N(N-1)/2 + S*N*N.
// Valid rows grouped by atom i ascending; within group: forward entries
// (triu j>i, then (s,j) lex) then backward entries (triu a<i, then (s,a) lex)
// — reproducing the reference's stable argsort. Invalid tail = (-1,-1,0,0,0,0).
//
// R3: same as R2 with the fp-contract pragma hoisted to file scope (compile fix).

#define WAVE 64
#define MAX_SHIFTS 64

__device__ __forceinline__ bool pv_fwd(float fx, float fy, float fz,
                                       const float* __restrict__ pos, int j,
                                       float sx, float sy, float sz, float cutoff) {
  float dx = fx - pos[j * 3 + 0] + sx;
  float dy = fy - pos[j * 3 + 1] + sy;
  float dz = fz - pos[j * 3 + 2] + sz;
  float d2 = dx * dx + dy * dy + dz * dz;  // numpy order, no fma (file-scope pragma)
  return sqrtf(d2) < cutoff;
}

__device__ __forceinline__ bool pv_bwd(const float* __restrict__ pos, int a,
                                       float fx, float fy, float fz,
                                       float sx, float sy, float sz, float cutoff) {
  float dx = pos[a * 3 + 0] - fx + sx;
  float dy = pos[a * 3 + 1] - fy + sy;
  float dz = pos[a * 3 + 2] - fz + sz;
  float d2 = dx * dx + dy * dy + dz * dz;
  return sqrtf(d2) < cutoff;
}

__device__ __forceinline__ void load_shift_vecs(const float* __restrict__ box,
                                                const int* __restrict__ shifts,
                                                int S, float* sv, int tid, int nthreads) {
  for (int s = tid; s < S; s += nthreads) {
    float s0 = (float)shifts[s * 3 + 0];
    float s1 = (float)shifts[s * 3 + 1];
    float s2 = (float)shifts[s * 3 + 2];
    sv[s * 3 + 0] = s0 * box[0] + s1 * box[3] + s2 * box[6];
    sv[s * 3 + 1] = s0 * box[1] + s1 * box[4] + s2 * box[7];
    sv[s * 3 + 2] = s0 * box[2] + s1 * box[5] + s2 * box[8];
  }
}

// conservative: can the interval [lo,hi] of achievable dx intersect (-cut,cut)?
__device__ __forceinline__ bool axis_ok(float lo, float hi, float cutpad) {
  return (hi > -cutpad) && (lo < cutpad);
}

__global__ void k_fill(float4* __restrict__ out, long n4, long neg4,
                       float* __restrict__ outf, long ntail_lo, long ntail_hi) {
  long i = (long)blockIdx.x * blockDim.x + threadIdx.x;
  long stride = (long)gridDim.x * blockDim.x;
  const float4 neg = make_float4(-1.f, -1.f, -1.f, -1.f);
  const float4 zer = make_float4(0.f, 0.f, 0.f, 0.f);
  for (long k = i; k < n4; k += stride) out[k] = (k < neg4) ? neg : zer;
  for (long k = ntail_lo + i; k < ntail_hi; k += stride) outf[k] = 0.f;
}

__global__ __launch_bounds__(256) void k_count(
    const float* __restrict__ pos, const float* __restrict__ box,
    const int* __restrict__ shifts, const float* __restrict__ cutp,
    int N, int S, int* __restrict__ count) {
  __shared__ float sv[MAX_SHIFTS * 3];
  __shared__ float bred[4][6];
  __shared__ int rf[4], rb[4];
  int atom = blockIdx.x;
  int t = threadIdx.x;
  float cut = cutp[0];
  float cutpad = cut + fmaxf(cut * 1e-5f, 1e-5f);  // covers sqrt-rounding edge
  load_shift_vecs(box, shifts, S, sv, t, blockDim.x);

  // block-redundant exact position bounds (fmin/fmax: order-independent)
  float mnx = 1e30f, mny = 1e30f, mnz = 1e30f, mxx = -1e30f, mxy = -1e30f, mxz = -1e30f;
  for (int i = t; i < N; i += blockDim.x) {
    float x = pos[3 * i + 0], y = pos[3 * i + 1], z = pos[3 * i + 2];
    mnx = fminf(mnx, x); mny = fminf(mny, y); mnz = fminf(mnz, z);
    mxx = fmaxf(mxx, x); mxy = fmaxf(mxy, y); mxz = fmaxf(mxz, z);
  }
  for (int off = 32; off; off >>= 1) {
    mnx = fminf(mnx, __shfl_xor(mnx, off)); mny = fminf(mny, __shfl_xor(mny, off));
    mnz = fminf(mnz, __shfl_xor(mnz, off)); mxx = fmaxf(mxx, __shfl_xor(mxx, off));
    mxy = fmaxf(mxy, __shfl_xor(mxy, off)); mxz = fmaxf(mxz, __shfl_xor(mxz, off));
  }
  int w = t >> 6;
  if ((t & 63) == 0) {
    bred[w][0] = mnx; bred[w][1] = mny; bred[w][2] = mnz;
    bred[w][3] = mxx; bred[w][4] = mxy; bred[w][5] = mxz;
  }
  __syncthreads();
  int nw = blockDim.x >> 6;
  mnx = bred[0][0]; mny = bred[0][1]; mnz = bred[0][2];
  mxx = bred[0][3]; mxy = bred[0][4]; mxz = bred[0][5];
  for (int ww = 1; ww < nw; ww++) {
    mnx = fminf(mnx, bred[ww][0]); mny = fminf(mny, bred[ww][1]); mnz = fminf(mnz, bred[ww][2]);
    mxx = fmaxf(mxx, bred[ww][3]); mxy = fmaxf(mxy, bred[ww][4]); mxz = fmaxf(mxz, bred[ww][5]);
  }

  float pix = pos[3 * atom + 0], piy = pos[3 * atom + 1], piz = pos[3 * atom + 2];
  int cf = 0, cb = 0;
  // fwd triu: j in (atom, N)
  for (int j = atom + 1 + t; j < N; j += blockDim.x)
    if (pv_fwd(pix, piy, piz, pos, j, 0.f, 0.f, 0.f, cut)) cf++;
  // bwd triu: a in [0, atom)
  for (int a = t; a < atom; a += blockDim.x)
    if (pv_bwd(pos, a, pix, piy, piz, 0.f, 0.f, 0.f, cut)) cb++;

  for (int s = 0; s < S; s++) {
    float svx = sv[3 * s + 0], svy = sv[3 * s + 1], svz = sv[3 * s + 2];
    // fwd: dx = pix - pjx + svx, pjx in [mn,mx]
    bool af = axis_ok((pix - mxx) + svx, (pix - mnx) + svx, cutpad) &&
              axis_ok((piy - mxy) + svy, (piy - mny) + svy, cutpad) &&
              axis_ok((piz - mxz) + svz, (piz - mnz) + svz, cutpad);
    if (af) {
      for (int j = t; j < N; j += blockDim.x)
        if (pv_fwd(pix, piy, piz, pos, j, svx, svy, svz, cut)) cf++;
    }
    // bwd: dx = pax - pix + svx, pax in [mn,mx]
    bool ab = axis_ok((mnx - pix) + svx, (mxx - pix) + svx, cutpad) &&
              axis_ok((mny - piy) + svy, (mxy - piy) + svy, cutpad) &&
              axis_ok((mnz - piz) + svz, (mxz - piz) + svz, cutpad);
    if (ab) {
      for (int a = t; a < N; a += blockDim.x)
        if (pv_bwd(pos, a, pix, piy, piz, svx, svy, svz, cut)) cb++;
    }
  }
  for (int off = 32; off; off >>= 1) {
    cf += __shfl_down(cf, off);
    cb += __shfl_down(cb, off);
  }
  if ((t & 63) == 0) { rf[w] = cf; rb[w] = cb; }
  __syncthreads();
  if (t == 0) {
    int f = 0, b = 0;
    for (int ww = 0; ww < nw; ww++) { f += rf[ww]; b += rb[ww]; }
    count[2 * atom + 0] = f;
    count[2 * atom + 1] = b;
  }
}

__global__ __launch_bounds__(64) void k_write(
    const float* __restrict__ pos, const float* __restrict__ box,
    const int* __restrict__ shifts, const float* __restrict__ cutp,
    int N, int S, const int* __restrict__ count,
    float* __restrict__ out, long M) {
  __shared__ float sv[MAX_SHIFTS * 3];
  int g = blockIdx.x;
  int atom = g >> 1;
  int dir = g & 1;  // 0 = forward (atom is pi), 1 = backward (atom is pj)
  int lane = threadIdx.x;  // one wave
  float cut = cutp[0];
  float cutpad = cut + fmaxf(cut * 1e-5f, 1e-5f);
  load_shift_vecs(box, shifts, S, sv, lane, 64);

  // single-wave exact bounds (same values as k_count: fmin/fmax exact)
  float mnx = 1e30f, mny = 1e30f, mnz = 1e30f, mxx = -1e30f, mxy = -1e30f, mxz = -1e30f;
  for (int i = lane; i < N; i += 64) {
    float x = pos[3 * i + 0], y = pos[3 * i + 1], z = pos[3 * i + 2];
    mnx = fminf(mnx, x); mny = fminf(mny, y); mnz = fminf(mnz, z);
    mxx = fmaxf(mxx, x); mxy = fmaxf(mxy, y); mxz = fmaxf(mxz, z);
  }
  for (int off = 32; off; off >>= 1) {
    mnx = fminf(mnx, __shfl_xor(mnx, off)); mny = fminf(mny, __shfl_xor(mny, off));
    mnz = fminf(mnz, __shfl_xor(mnz, off)); mxx = fmaxf(mxx, __shfl_xor(mxx, off));
    mxy = fmaxf(mxy, __shfl_xor(mxy, off)); mxz = fmaxf(mxz, __shfl_xor(mxz, off));
  }
  __syncthreads();

  // fused exclusive scan: base = sum count[0..g)
  int ps = 0;
  for (int i = lane; i < g; i += 64) ps += count[i];
  for (int off = 32; off; off >>= 1) ps += __shfl_xor(ps, off);
  long base = ps;

  float* __restrict__ out_i = out;
  float* __restrict__ out_j = out + M;
  float* __restrict__ out_off = out + 2 * M;
  float* __restrict__ out_v = out + 5 * M;

  float pix = pos[3 * atom + 0], piy = pos[3 * atom + 1], piz = pos[3 * atom + 2];
  float fatom = (float)atom;
  int running = 0;

  // segment 1: triu (shift = 0, output offset = ∓0)
  {
    int n = (dir == 0) ? (N - 1 - atom) : atom;
    int j0 = (dir == 0) ? (atom + 1) : 0;
    float oz0 = (dir == 0) ? -0.0f : 0.0f;  // ref: -shifts for first half
    for (int c0 = 0; c0 < n; c0 += WAVE) {
      int c = c0 + lane;
      bool v = false;
      int other = j0 + c;
      if (c < n) {
        v = (dir == 0) ? pv_fwd(pix, piy, piz, pos, other, 0.f, 0.f, 0.f, cut)
                       : pv_bwd(pos, other, pix, piy, piz, 0.f, 0.f, 0.f, cut);
      }
      unsigned long long m = __ballot(v);
      if (v) {
        int rank = __popcll(m & ((1ULL << lane) - 1ULL));
        long row = base + running + rank;
        out_i[row] = fatom;
        out_j[row] = (float)other;
        out_off[row * 3 + 0] = oz0;
        out_off[row * 3 + 1] = oz0;
        out_off[row * 3 + 2] = oz0;
        out_v[row] = 1.0f;
      }
      running += __popcll(m);
    }
  }
  // segments 2..: shifts in order, pruned identically-conservatively
  for (int s = 0; s < S; s++) {
    float svx = sv[3 * s + 0], svy = sv[3 * s + 1], svz = sv[3 * s + 2];
    bool active;
    if (dir == 0) {
      active = axis_ok((pix - mxx) + svx, (pix - mnx) + svx, cutpad) &&
               axis_ok((piy - mxy) + svy, (piy - mny) + svy, cutpad) &&
               axis_ok((piz - mxz) + svz, (piz - mnz) + svz, cutpad);
    } else {
      active = axis_ok((mnx - pix) + svx, (mxx - pix) + svx, cutpad) &&
               axis_ok((mny - piy) + svy, (mxy - piy) + svy, cutpad) &&
               axis_ok((mnz - piz) + svz, (mxz - piz) + svz, cutpad);
    }
    if (!active) continue;  // uniform: skipped shifts contribute no valid rows
    float ox = (dir == 0) ? -svx : svx;
    float oy = (dir == 0) ? -svy : svy;
    float oz = (dir == 0) ? -svz : svz;
    for (int c0 = 0; c0 < N; c0 += WAVE) {
      int other = c0 + lane;
      bool v = false;
      if (other < N) {
        v = (dir == 0) ? pv_fwd(pix, piy, piz, pos, other, svx, svy, svz, cut)
                       : pv_bwd(pos, other, pix, piy, piz, svx, svy, svz, cut);
      }
      unsigned long long m = __ballot(v);
      if (v) {
        int rank = __popcll(m & ((1ULL << lane) - 1ULL));
        long row = base + running + rank;
        out_i[row] = fatom;
        out_j[row] = (float)other;
        out_off[row * 3 + 0] = ox;
        out_off[row * 3 + 1] = oy;
        out_off[row * 3 + 2] = oz;
        out_v[row] = 1.0f;
      }
      running += __popcll(m);
    }
  }
}

extern "C" void kernel_launch(void* const* d_in, const int* in_sizes, int n_in,
                              void* d_out, int out_size, void* d_ws, size_t ws_size,
                              hipStream_t stream) {
  const float* pos = (const float*)d_in[0];
  const float* box = (const float*)d_in[1];
  const int* shifts = (const int*)d_in[2];
  const float* cutp = (const float*)d_in[3];
  int N = in_sizes[0] / 3;
  int S = in_sizes[2] / 3;
  long M = (long)out_size / 6;
  float* out = (float*)d_out;

  int* count = (int*)d_ws;

  long n4 = (long)out_size / 4;
  long neg4 = (2 * M) / 4;
  long tail_lo = n4 * 4, tail_hi = (long)out_size;

  hipLaunchKernelGGL(k_count, dim3(N), dim3(256), 0, stream,
                     pos, box, shifts, cutp, N, S, count);
  hipLaunchKernelGGL(k_fill, dim3(2048), dim3(256), 0, stream,
                     (float4*)out, n4, neg4, out, tail_lo, tail_hi);
  hipLaunchKernelGGL(k_write, dim3(2 * N), dim3(64), 0, stream,
                     pos, box, shifts, cutp, N, S, count, out, M);
}

// Round 5
// 102.902 us; speedup vs baseline: 1.8005x; 1.3100x over previous
//
#include <hip/hip_runtime.h>

#pragma clang fp contract(off)

// TorchNeighborList for MI355X — R5 (= R4 with native vector type for
// __builtin_nontemporal_store).
// Output (floats): [idx_i (M)] [idx_j (M)] [offset (M*3)] [valid (M)], M = 2P.
// Valid rows grouped by atom asc; per atom: fwd entries (triu j>i, then (s,j)),
// then bwd entries (triu a<i, then (s,a)) — reproduces reference stable argsort.
// Invalid tail = (-1,-1,0,0,0,0).

#define MAX_SHIFTS 64
#define FILL_ITERS 16  // float4s per thread per fill block (256 thr -> 4096/blk)

typedef float f32x4 __attribute__((ext_vector_type(4)));

__device__ __forceinline__ bool pv_fwd(float fx, float fy, float fz,
                                       const float* __restrict__ pos, int j,
                                       float sx, float sy, float sz, float cutoff) {
  float dx = fx - pos[j * 3 + 0] + sx;
  float dy = fy - pos[j * 3 + 1] + sy;
  float dz = fz - pos[j * 3 + 2] + sz;
  float d2 = dx * dx + dy * dy + dz * dz;  // numpy order, no fma (file pragma)
  return sqrtf(d2) < cutoff;
}

__device__ __forceinline__ bool pv_bwd(const float* __restrict__ pos, int a,
                                       float fx, float fy, float fz,
                                       float sx, float sy, float sz, float cutoff) {
  float dx = pos[a * 3 + 0] - fx + sx;
  float dy = pos[a * 3 + 1] - fy + sy;
  float dz = pos[a * 3 + 2] - fz + sz;
  float d2 = dx * dx + dy * dy + dz * dz;
  return sqrtf(d2) < cutoff;
}

__device__ __forceinline__ void load_shift_vecs(const float* __restrict__ box,
                                                const int* __restrict__ shifts,
                                                int S, float* sv, int tid, int nthreads) {
  for (int s = tid; s < S; s += nthreads) {
    float s0 = (float)shifts[s * 3 + 0];
    float s1 = (float)shifts[s * 3 + 1];
    float s2 = (float)shifts[s * 3 + 2];
    sv[s * 3 + 0] = s0 * box[0] + s1 * box[3] + s2 * box[6];
    sv[s * 3 + 1] = s0 * box[1] + s1 * box[4] + s2 * box[7];
    sv[s * 3 + 2] = s0 * box[2] + s1 * box[5] + s2 * box[8];
  }
}

__device__ __forceinline__ bool axis_ok(float lo, float hi, float cutpad) {
  return (hi > -cutpad) && (lo < cutpad);
}

__global__ __launch_bounds__(256) void k_count(
    const float* __restrict__ pos, const float* __restrict__ box,
    const int* __restrict__ shifts, const float* __restrict__ cutp,
    int N, int S, int* __restrict__ count) {
  __shared__ float sv[MAX_SHIFTS * 3];
  __shared__ float bred[4][6];
  __shared__ int rf[4], rb[4];
  int atom = blockIdx.x;
  int t = threadIdx.x;
  float cut = cutp[0];
  float cutpad = cut + fmaxf(cut * 1e-5f, 1e-5f);
  load_shift_vecs(box, shifts, S, sv, t, blockDim.x);

  float mnx = 1e30f, mny = 1e30f, mnz = 1e30f, mxx = -1e30f, mxy = -1e30f, mxz = -1e30f;
  for (int i = t; i < N; i += blockDim.x) {
    float x = pos[3 * i + 0], y = pos[3 * i + 1], z = pos[3 * i + 2];
    mnx = fminf(mnx, x); mny = fminf(mny, y); mnz = fminf(mnz, z);
    mxx = fmaxf(mxx, x); mxy = fmaxf(mxy, y); mxz = fmaxf(mxz, z);
  }
  for (int off = 32; off; off >>= 1) {
    mnx = fminf(mnx, __shfl_xor(mnx, off)); mny = fminf(mny, __shfl_xor(mny, off));
    mnz = fminf(mnz, __shfl_xor(mnz, off)); mxx = fmaxf(mxx, __shfl_xor(mxx, off));
    mxy = fmaxf(mxy, __shfl_xor(mxy, off)); mxz = fmaxf(mxz, __shfl_xor(mxz, off));
  }
  int w = t >> 6;
  if ((t & 63) == 0) {
    bred[w][0] = mnx; bred[w][1] = mny; bred[w][2] = mnz;
    bred[w][3] = mxx; bred[w][4] = mxy; bred[w][5] = mxz;
  }
  __syncthreads();
  int nw = blockDim.x >> 6;
  mnx = bred[0][0]; mny = bred[0][1]; mnz = bred[0][2];
  mxx = bred[0][3]; mxy = bred[0][4]; mxz = bred[0][5];
  for (int ww = 1; ww < nw; ww++) {
    mnx = fminf(mnx, bred[ww][0]); mny = fminf(mny, bred[ww][1]); mnz = fminf(mnz, bred[ww][2]);
    mxx = fmaxf(mxx, bred[ww][3]); mxy = fmaxf(mxy, bred[ww][4]); mxz = fmaxf(mxz, bred[ww][5]);
  }

  float pix = pos[3 * atom + 0], piy = pos[3 * atom + 1], piz = pos[3 * atom + 2];
  int cf = 0, cb = 0;
  for (int j = atom + 1 + t; j < N; j += blockDim.x)
    if (pv_fwd(pix, piy, piz, pos, j, 0.f, 0.f, 0.f, cut)) cf++;
  for (int a = t; a < atom; a += blockDim.x)
    if (pv_bwd(pos, a, pix, piy, piz, 0.f, 0.f, 0.f, cut)) cb++;

  for (int s = 0; s < S; s++) {
    float svx = sv[3 * s + 0], svy = sv[3 * s + 1], svz = sv[3 * s + 2];
    bool af = axis_ok((pix - mxx) + svx, (pix - mnx) + svx, cutpad) &&
              axis_ok((piy - mxy) + svy, (piy - mny) + svy, cutpad) &&
              axis_ok((piz - mxz) + svz, (piz - mnz) + svz, cutpad);
    if (af) {
      for (int j = t; j < N; j += blockDim.x)
        if (pv_fwd(pix, piy, piz, pos, j, svx, svy, svz, cut)) cf++;
    }
    bool ab = axis_ok((mnx - pix) + svx, (mxx - pix) + svx, cutpad) &&
              axis_ok((mny - piy) + svy, (mxy - piy) + svy, cutpad) &&
              axis_ok((mnz - piz) + svz, (mxz - piz) + svz, cutpad);
    if (ab) {
      for (int a = t; a < N; a += blockDim.x)
        if (pv_bwd(pos, a, pix, piy, piz, svx, svy, svz, cut)) cb++;
    }
  }
  for (int off = 32; off; off >>= 1) {
    cf += __shfl_down(cf, off);
    cb += __shfl_down(cb, off);
  }
  if ((t & 63) == 0) { rf[w] = cf; rb[w] = cb; }
  __syncthreads();
  if (t == 0) {
    int f = 0, b = 0;
    for (int ww = 0; ww < nw; ww++) { f += rf[ww]; b += rb[ww]; }
    count[2 * atom + 0] = f;
    count[2 * atom + 1] = b;
  }
}

// single-block exclusive scan: start[i] = sum count[0..i), start[n2] = total
__global__ __launch_bounds__(256) void k_scan(const int* __restrict__ count,
                                              int* __restrict__ start, int n2) {
  __shared__ int part[256];
  int t = threadIdx.x;
  int chunk = (n2 + 255) >> 8;
  int lo = t * chunk;
  int hi = min(lo + chunk, n2);
  int s = 0;
  for (int i = lo; i < hi; i++) s += count[i];
  part[t] = s;
  __syncthreads();
  for (int off = 1; off < 256; off <<= 1) {
    int v = (t >= off) ? part[t - off] : 0;
    __syncthreads();
    part[t] += v;
    __syncthreads();
  }
  int run = part[t] - s;  // exclusive prefix for this chunk
  for (int i = lo; i < hi; i++) { start[i] = run; run += count[i]; }
  if (t == 255) start[n2] = part[255];
}

// fused: blocks [0, NWB) write valid rows (1 wave per (atom,dir) group);
//        blocks [NWB, ..) fill defaults to all elements >= per-segment valid-end.
__global__ __launch_bounds__(256) void k_main(
    const float* __restrict__ pos, const float* __restrict__ box,
    const int* __restrict__ shifts, const float* __restrict__ cutp,
    int N, int S, const int* __restrict__ start,
    float* __restrict__ out, long M, long n4, int NWB) {
  __shared__ float sv[MAX_SHIFTS * 3];
  int t = threadIdx.x;

  if ((int)blockIdx.x < NWB) {
    float cut = cutp[0];
    float cutpad = cut + fmaxf(cut * 1e-5f, 1e-5f);
    load_shift_vecs(box, shifts, S, sv, t, 256);
    __syncthreads();
    int w = t >> 6, lane = t & 63;
    int g = blockIdx.x * 4 + w;
    if (g >= 2 * N) return;
    int atom = g >> 1;
    int dir = g & 1;  // 0 = fwd (atom is pi), 1 = bwd (atom is pj)

    // per-wave exact bounds (fmin/fmax order-independent -> same as k_count)
    float mnx = 1e30f, mny = 1e30f, mnz = 1e30f, mxx = -1e30f, mxy = -1e30f, mxz = -1e30f;
    for (int i = lane; i < N; i += 64) {
      float x = pos[3 * i + 0], y = pos[3 * i + 1], z = pos[3 * i + 2];
      mnx = fminf(mnx, x); mny = fminf(mny, y); mnz = fminf(mnz, z);
      mxx = fmaxf(mxx, x); mxy = fmaxf(mxy, y); mxz = fmaxf(mxz, z);
    }
    for (int off = 32; off; off >>= 1) {
      mnx = fminf(mnx, __shfl_xor(mnx, off)); mny = fminf(mny, __shfl_xor(mny, off));
      mnz = fminf(mnz, __shfl_xor(mnz, off)); mxx = fmaxf(mxx, __shfl_xor(mxx, off));
      mxy = fmaxf(mxy, __shfl_xor(mxy, off)); mxz = fmaxf(mxz, __shfl_xor(mxz, off));
    }

    long base = start[g];
    float* __restrict__ out_i = out;
    float* __restrict__ out_j = out + M;
    float* __restrict__ out_off = out + 2 * M;
    float* __restrict__ out_v = out + 5 * M;

    float pix = pos[3 * atom + 0], piy = pos[3 * atom + 1], piz = pos[3 * atom + 2];
    float fatom = (float)atom;
    int running = 0;

    // segment 1: triu (shift 0; first half offset = -0)
    {
      int n = (dir == 0) ? (N - 1 - atom) : atom;
      int j0 = (dir == 0) ? (atom + 1) : 0;
      float oz0 = (dir == 0) ? -0.0f : 0.0f;
      for (int c0 = 0; c0 < n; c0 += 64) {
        int c = c0 + lane;
        bool v = false;
        int other = j0 + c;
        if (c < n) {
          v = (dir == 0) ? pv_fwd(pix, piy, piz, pos, other, 0.f, 0.f, 0.f, cut)
                         : pv_bwd(pos, other, pix, piy, piz, 0.f, 0.f, 0.f, cut);
        }
        unsigned long long m = __ballot(v);
        if (v) {
          int rank = __popcll(m & ((1ULL << lane) - 1ULL));
          long row = base + running + rank;
          out_i[row] = fatom;
          out_j[row] = (float)other;
          out_off[row * 3 + 0] = oz0;
          out_off[row * 3 + 1] = oz0;
          out_off[row * 3 + 2] = oz0;
          out_v[row] = 1.0f;
        }
        running += __popcll(m);
      }
    }
    // shift segments (pruned conservatively, identical predicate to k_count)
    for (int s = 0; s < S; s++) {
      float svx = sv[3 * s + 0], svy = sv[3 * s + 1], svz = sv[3 * s + 2];
      bool active;
      if (dir == 0) {
        active = axis_ok((pix - mxx) + svx, (pix - mnx) + svx, cutpad) &&
                 axis_ok((piy - mxy) + svy, (piy - mny) + svy, cutpad) &&
                 axis_ok((piz - mxz) + svz, (piz - mnz) + svz, cutpad);
      } else {
        active = axis_ok((mnx - pix) + svx, (mxx - pix) + svx, cutpad) &&
                 axis_ok((mny - piy) + svy, (mxy - piy) + svy, cutpad) &&
                 axis_ok((mnz - piz) + svz, (mxz - piz) + svz, cutpad);
      }
      if (!active) continue;
      float ox = (dir == 0) ? -svx : svx;
      float oy = (dir == 0) ? -svy : svy;
      float oz = (dir == 0) ? -svz : svz;
      for (int c0 = 0; c0 < N; c0 += 64) {
        int other = c0 + lane;
        bool v = false;
        if (other < N) {
          v = (dir == 0) ? pv_fwd(pix, piy, piz, pos, other, svx, svy, svz, cut)
                         : pv_bwd(pos, other, pix, piy, piz, svx, svy, svz, cut);
        }
        unsigned long long m = __ballot(v);
        if (v) {
          int rank = __popcll(m & ((1ULL << lane) - 1ULL));
          long row = base + running + rank;
          out_i[row] = fatom;
          out_j[row] = (float)other;
          out_off[row * 3 + 0] = ox;
          out_off[row * 3 + 1] = oy;
          out_off[row * 3 + 2] = oz;
          out_v[row] = 1.0f;
        }
        running += __popcll(m);
      }
    }
  } else {
    // ---- fill part: defaults for everything at/after each segment's valid end
    long fb = (long)blockIdx.x - NWB;
    long kbase = fb * (256L * FILL_ITERS);
    long total = (long)start[2 * N];
    long E0 = total;                 // idx_i data end (element units)
    long E1 = M + total;             // idx_j
    long E2 = 2 * M + 3 * total;     // offsets
    long E3 = 5 * M + total;         // valid
    const f32x4 neg = {-1.f, -1.f, -1.f, -1.f};
    const f32x4 zer = {0.f, 0.f, 0.f, 0.f};
    f32x4* __restrict__ out4 = (f32x4*)out;
    for (int it = 0; it < FILL_ITERS; it++) {
      long k = kbase + (long)it * 256 + t;
      if (k >= n4) break;
      long e = k << 2;
      long ve = (e < M) ? E0 : ((e < 2 * M) ? E1 : ((e < 5 * M) ? E2 : E3));
      if (e + 4 <= ve) continue;       // inside valid data: owned by write waves
      bool isneg = (e < 2 * M);        // float4 never straddles segment bounds (M%4==0)
      if (e >= ve) {
        __builtin_nontemporal_store(isneg ? neg : zer, &out4[k]);
      } else {
        float dv = isneg ? -1.f : 0.f;
        for (int q = 0; q < 4; q++)
          if (e + q >= ve) out[e + q] = dv;
      }
    }
  }
}

extern "C" void kernel_launch(void* const* d_in, const int* in_sizes, int n_in,
                              void* d_out, int out_size, void* d_ws, size_t ws_size,
                              hipStream_t stream) {
  const float* pos = (const float*)d_in[0];
  const float* box = (const float*)d_in[1];
  const int* shifts = (const int*)d_in[2];
  const float* cutp = (const float*)d_in[3];
  int N = in_sizes[0] / 3;
  int S = in_sizes[2] / 3;
  long M = (long)out_size / 6;
  float* out = (float*)d_out;

  int* count = (int*)d_ws;
  int* start = count + 2 * N;  // start[0..2N], start[2N] = total

  long n4 = (long)out_size / 4;
  int NWB = (2 * N + 3) / 4;
  int NFB = (int)((n4 + (256L * FILL_ITERS) - 1) / (256L * FILL_ITERS));

  hipLaunchKernelGGL(k_count, dim3(N), dim3(256), 0, stream,
                     pos, box, shifts, cutp, N, S, count);
  hipLaunchKernelGGL(k_scan, dim3(1), dim3(256), 0, stream, count, start, 2 * N);
  hipLaunchKernelGGL(k_main, dim3(NWB + NFB), dim3(256), 0, stream,
                     pos, box, shifts, cutp, N, S, start, out, M, n4, NWB);
}

// Round 6
// 94.284 us; speedup vs baseline: 1.9651x; 1.0914x over previous
//
#include <hip/hip_runtime.h>

#pragma clang fp contract(off)

// TorchNeighborList for MI355X — R6.
// Output (floats): [idx_i (M)] [idx_j (M)] [offset (M*3)] [valid (M)], M = 2P.
// Valid rows grouped by atom asc; per atom: fwd entries (triu j>i, then (s,j)),
// then bwd entries (triu a<i, then (s,a)) — reproduces reference stable argsort.
// Invalid tail = (-1,-1,0,0,0,0).
//
// R6: 2 kernels. k_count (per-atom fwd/bwd counts, shift-pruned).
// k_main: write role (1 wave per (atom,dir), base = own prefix-sum of counts)
//         + fill role (uniform fast path: 16 unrolled plain dwordx4 stores).

#define MAX_SHIFTS 64
#define FILL_ITERS 16  // float4s per thread per fill block (256 thr -> 64 KB/blk)

typedef float f32x4 __attribute__((ext_vector_type(4)));

__device__ __forceinline__ bool pv_fwd(float fx, float fy, float fz,
                                       const float* __restrict__ pos, int j,
                                       float sx, float sy, float sz, float cutoff) {
  float dx = fx - pos[j * 3 + 0] + sx;
  float dy = fy - pos[j * 3 + 1] + sy;
  float dz = fz - pos[j * 3 + 2] + sz;
  float d2 = dx * dx + dy * dy + dz * dz;  // numpy order, no fma (file pragma)
  return sqrtf(d2) < cutoff;
}

__device__ __forceinline__ bool pv_bwd(const float* __restrict__ pos, int a,
                                       float fx, float fy, float fz,
                                       float sx, float sy, float sz, float cutoff) {
  float dx = pos[a * 3 + 0] - fx + sx;
  float dy = pos[a * 3 + 1] - fy + sy;
  float dz = pos[a * 3 + 2] - fz + sz;
  float d2 = dx * dx + dy * dy + dz * dz;
  return sqrtf(d2) < cutoff;
}

__device__ __forceinline__ void load_shift_vecs(const float* __restrict__ box,
                                                const int* __restrict__ shifts,
                                                int S, float* sv, int tid, int nthreads) {
  for (int s = tid; s < S; s += nthreads) {
    float s0 = (float)shifts[s * 3 + 0];
    float s1 = (float)shifts[s * 3 + 1];
    float s2 = (float)shifts[s * 3 + 2];
    sv[s * 3 + 0] = s0 * box[0] + s1 * box[3] + s2 * box[6];
    sv[s * 3 + 1] = s0 * box[1] + s1 * box[4] + s2 * box[7];
    sv[s * 3 + 2] = s0 * box[2] + s1 * box[5] + s2 * box[8];
  }
}

__device__ __forceinline__ bool axis_ok(float lo, float hi, float cutpad) {
  return (hi > -cutpad) && (lo < cutpad);
}

__global__ __launch_bounds__(256) void k_count(
    const float* __restrict__ pos, const float* __restrict__ box,
    const int* __restrict__ shifts, const float* __restrict__ cutp,
    int N, int S, int* __restrict__ count) {
  __shared__ float sv[MAX_SHIFTS * 3];
  __shared__ float bred[4][6];
  __shared__ int rf[4], rb[4];
  int atom = blockIdx.x;
  int t = threadIdx.x;
  float cut = cutp[0];
  float cutpad = cut + fmaxf(cut * 1e-5f, 1e-5f);
  load_shift_vecs(box, shifts, S, sv, t, blockDim.x);

  float mnx = 1e30f, mny = 1e30f, mnz = 1e30f, mxx = -1e30f, mxy = -1e30f, mxz = -1e30f;
  for (int i = t; i < N; i += blockDim.x) {
    float x = pos[3 * i + 0], y = pos[3 * i + 1], z = pos[3 * i + 2];
    mnx = fminf(mnx, x); mny = fminf(mny, y); mnz = fminf(mnz, z);
    mxx = fmaxf(mxx, x); mxy = fmaxf(mxy, y); mxz = fmaxf(mxz, z);
  }
  for (int off = 32; off; off >>= 1) {
    mnx = fminf(mnx, __shfl_xor(mnx, off)); mny = fminf(mny, __shfl_xor(mny, off));
    mnz = fminf(mnz, __shfl_xor(mnz, off)); mxx = fmaxf(mxx, __shfl_xor(mxx, off));
    mxy = fmaxf(mxy, __shfl_xor(mxy, off)); mxz = fmaxf(mxz, __shfl_xor(mxz, off));
  }
  int w = t >> 6;
  if ((t & 63) == 0) {
    bred[w][0] = mnx; bred[w][1] = mny; bred[w][2] = mnz;
    bred[w][3] = mxx; bred[w][4] = mxy; bred[w][5] = mxz;
  }
  __syncthreads();
  int nw = blockDim.x >> 6;
  mnx = bred[0][0]; mny = bred[0][1]; mnz = bred[0][2];
  mxx = bred[0][3]; mxy = bred[0][4]; mxz = bred[0][5];
  for (int ww = 1; ww < nw; ww++) {
    mnx = fminf(mnx, bred[ww][0]); mny = fminf(mny, bred[ww][1]); mnz = fminf(mnz, bred[ww][2]);
    mxx = fmaxf(mxx, bred[ww][3]); mxy = fmaxf(mxy, bred[ww][4]); mxz = fmaxf(mxz, bred[ww][5]);
  }

  float pix = pos[3 * atom + 0], piy = pos[3 * atom + 1], piz = pos[3 * atom + 2];
  int cf = 0, cb = 0;
  for (int j = atom + 1 + t; j < N; j += blockDim.x)
    if (pv_fwd(pix, piy, piz, pos, j, 0.f, 0.f, 0.f, cut)) cf++;
  for (int a = t; a < atom; a += blockDim.x)
    if (pv_bwd(pos, a, pix, piy, piz, 0.f, 0.f, 0.f, cut)) cb++;

  for (int s = 0; s < S; s++) {
    float svx = sv[3 * s + 0], svy = sv[3 * s + 1], svz = sv[3 * s + 2];
    bool af = axis_ok((pix - mxx) + svx, (pix - mnx) + svx, cutpad) &&
              axis_ok((piy - mxy) + svy, (piy - mny) + svy, cutpad) &&
              axis_ok((piz - mxz) + svz, (piz - mnz) + svz, cutpad);
    if (af) {
      for (int j = t; j < N; j += blockDim.x)
        if (pv_fwd(pix, piy, piz, pos, j, svx, svy, svz, cut)) cf++;
    }
    bool ab = axis_ok((mnx - pix) + svx, (mxx - pix) + svx, cutpad) &&
              axis_ok((mny - piy) + svy, (mxy - piy) + svy, cutpad) &&
              axis_ok((mnz - piz) + svz, (mxz - piz) + svz, cutpad);
    if (ab) {
      for (int a = t; a < N; a += blockDim.x)
        if (pv_bwd(pos, a, pix, piy, piz, svx, svy, svz, cut)) cb++;
    }
  }
  for (int off = 32; off; off >>= 1) {
    cf += __shfl_down(cf, off);
    cb += __shfl_down(cb, off);
  }
  if ((t & 63) == 0) { rf[w] = cf; rb[w] = cb; }
  __syncthreads();
  if (t == 0) {
    int f = 0, b = 0;
    for (int ww = 0; ww < nw; ww++) { f += rf[ww]; b += rb[ww]; }
    count[2 * atom + 0] = f;
    count[2 * atom + 1] = b;
  }
}

// blocks [0, NWB): write valid rows (1 wave per (atom,dir) group; base from
//   own prefix-sum over count[]).
// blocks [NWB, ..): fill defaults; uniform blocks take a branch-free unrolled
//   store path, boundary blocks a per-element path. Disjoint from write role.
__global__ __launch_bounds__(256) void k_main(
    const float* __restrict__ pos, const float* __restrict__ box,
    const int* __restrict__ shifts, const float* __restrict__ cutp,
    int N, int S, const int* __restrict__ count,
    float* __restrict__ out, long M, long n4, int NWB) {
  __shared__ float sv[MAX_SHIFTS * 3];
  int t = threadIdx.x;
  int lane = t & 63, w = t >> 6;
  int n2 = 2 * N;

  if ((int)blockIdx.x < NWB) {
    float cut = cutp[0];
    float cutpad = cut + fmaxf(cut * 1e-5f, 1e-5f);
    load_shift_vecs(box, shifts, S, sv, t, 256);
    __syncthreads();
    int g = blockIdx.x * 4 + w;
    if (g >= n2) return;
    int atom = g >> 1;
    int dir = g & 1;  // 0 = fwd (atom is pi), 1 = bwd (atom is pj)

    // per-wave exact bounds (fmin/fmax order-independent -> same as k_count)
    float mnx = 1e30f, mny = 1e30f, mnz = 1e30f, mxx = -1e30f, mxy = -1e30f, mxz = -1e30f;
    for (int i = lane; i < N; i += 64) {
      float x = pos[3 * i + 0], y = pos[3 * i + 1], z = pos[3 * i + 2];
      mnx = fminf(mnx, x); mny = fminf(mny, y); mnz = fminf(mnz, z);
      mxx = fmaxf(mxx, x); mxy = fmaxf(mxy, y); mxz = fmaxf(mxz, z);
    }
    for (int off = 32; off; off >>= 1) {
      mnx = fminf(mnx, __shfl_xor(mnx, off)); mny = fminf(mny, __shfl_xor(mny, off));
      mnz = fminf(mnz, __shfl_xor(mnz, off)); mxx = fmaxf(mxx, __shfl_xor(mxx, off));
      mxy = fmaxf(mxy, __shfl_xor(mxy, off)); mxz = fmaxf(mxz, __shfl_xor(mxz, off));
    }

    // base = exclusive prefix sum of counts (exact integer sum, order-free)
    int pre = 0;
    for (int i = lane; i < g; i += 64) pre += count[i];
    for (int off = 32; off; off >>= 1) pre += __shfl_xor(pre, off);
    long base = pre;

    float* __restrict__ out_i = out;
    float* __restrict__ out_j = out + M;
    float* __restrict__ out_off = out + 2 * M;
    float* __restrict__ out_v = out + 5 * M;

    float pix = pos[3 * atom + 0], piy = pos[3 * atom + 1], piz = pos[3 * atom + 2];
    float fatom = (float)atom;
    int running = 0;

    // segment 1: triu (shift 0; first half offset = -0)
    {
      int n = (dir == 0) ? (N - 1 - atom) : atom;
      int j0 = (dir == 0) ? (atom + 1) : 0;
      float oz0 = (dir == 0) ? -0.0f : 0.0f;
      for (int c0 = 0; c0 < n; c0 += 64) {
        int c = c0 + lane;
        bool v = false;
        int other = j0 + c;
        if (c < n) {
          v = (dir == 0) ? pv_fwd(pix, piy, piz, pos, other, 0.f, 0.f, 0.f, cut)
                         : pv_bwd(pos, other, pix, piy, piz, 0.f, 0.f, 0.f, cut);
        }
        unsigned long long m = __ballot(v);
        if (v) {
          int rank = __popcll(m & ((1ULL << lane) - 1ULL));
          long row = base + running + rank;
          out_i[row] = fatom;
          out_j[row] = (float)other;
          out_off[row * 3 + 0] = oz0;
          out_off[row * 3 + 1] = oz0;
          out_off[row * 3 + 2] = oz0;
          out_v[row] = 1.0f;
        }
        running += __popcll(m);
      }
    }
    // shift segments (pruned conservatively, identical predicate to k_count)
    for (int s = 0; s < S; s++) {
      float svx = sv[3 * s + 0], svy = sv[3 * s + 1], svz = sv[3 * s + 2];
      bool active;
      if (dir == 0) {
        active = axis_ok((pix - mxx) + svx, (pix - mnx) + svx, cutpad) &&
                 axis_ok((piy - mxy) + svy, (piy - mny) + svy, cutpad) &&
                 axis_ok((piz - mxz) + svz, (piz - mnz) + svz, cutpad);
      } else {
        active = axis_ok((mnx - pix) + svx, (mxx - pix) + svx, cutpad) &&
                 axis_ok((mny - piy) + svy, (mxy - piy) + svy, cutpad) &&
                 axis_ok((mnz - piz) + svz, (mxz - piz) + svz, cutpad);
      }
      if (!active) continue;
      float ox = (dir == 0) ? -svx : svx;
      float oy = (dir == 0) ? -svy : svy;
      float oz = (dir == 0) ? -svz : svz;
      for (int c0 = 0; c0 < N; c0 += 64) {
        int other = c0 + lane;
        bool v = false;
        if (other < N) {
          v = (dir == 0) ? pv_fwd(pix, piy, piz, pos, other, svx, svy, svz, cut)
                         : pv_bwd(pos, other, pix, piy, piz, svx, svy, svz, cut);
        }
        unsigned long long m = __ballot(v);
        if (v) {
          int rank = __popcll(m & ((1ULL << lane) - 1ULL));
          long row = base + running + rank;
          out_i[row] = fatom;
          out_j[row] = (float)other;
          out_off[row * 3 + 0] = ox;
          out_off[row * 3 + 1] = oy;
          out_off[row * 3 + 2] = oz;
          out_v[row] = 1.0f;
        }
        running += __popcll(m);
      }
    }
  } else {
    // ---- fill role ----
    // total = sum of all counts (redundant per block; exact, order-free)
    int tot = 0;
    for (int i = lane; i < n2; i += 64) tot += count[i];
    for (int off = 32; off; off >>= 1) tot += __shfl_xor(tot, off);
    long total = tot;

    long fb = (long)blockIdx.x - NWB;
    long k_lo = fb * (256L * FILL_ITERS);
    long k_hi = k_lo + 256L * FILL_ITERS;
    if (k_hi > n4) k_hi = n4;
    long e_lo = k_lo << 2, e_hi = k_hi << 2;

    long E0 = total;              // idx_i valid end (element units)
    long E1 = M + total;          // idx_j
    long E2 = 2 * M + 3 * total;  // offsets
    long E3 = 5 * M + total;      // valid
    const f32x4 neg = {-1.f, -1.f, -1.f, -1.f};
    const f32x4 zer = {0.f, 0.f, 0.f, 0.f};
    f32x4* __restrict__ out4 = (f32x4*)out;

    int s0 = (e_lo < M) ? 0 : ((e_lo < 2 * M) ? 1 : ((e_lo < 5 * M) ? 2 : 3));
    long eh = e_hi - 1;
    int s1 = (eh < M) ? 0 : ((eh < 2 * M) ? 1 : ((eh < 5 * M) ? 2 : 3));
    long ve0 = (s0 == 0) ? E0 : ((s0 == 1) ? E1 : ((s0 == 2) ? E2 : E3));

    if ((k_hi - k_lo) == 256L * FILL_ITERS && s0 == s1 && e_lo >= ve0) {
      // uniform fast path: branch-free unrolled plain stores
      f32x4 val = (s0 < 2) ? neg : zer;
      f32x4* __restrict__ p = out4 + k_lo + t;
#pragma unroll
      for (int it = 0; it < FILL_ITERS; it++) p[(long)it * 256] = val;
    } else {
      // boundary path (few blocks): per-element logic
      for (int it = 0; it < FILL_ITERS; it++) {
        long k = k_lo + (long)it * 256 + t;
        if (k >= n4) break;
        long e = k << 2;
        long ve = (e < M) ? E0 : ((e < 2 * M) ? E1 : ((e < 5 * M) ? E2 : E3));
        if (e + 4 <= ve) continue;  // valid-data region: owned by write waves
        bool isneg = (e < 2 * M);   // float4 never straddles segments (M%4==0)
        if (e >= ve) {
          out4[k] = isneg ? neg : zer;
        } else {
          float dv = isneg ? -1.f : 0.f;
          for (int q = 0; q < 4; q++)
            if (e + q >= ve) out[e + q] = dv;
        }
      }
    }
  }
}

extern "C" void kernel_launch(void* const* d_in, const int* in_sizes, int n_in,
                              void* d_out, int out_size, void* d_ws, size_t ws_size,
                              hipStream_t stream) {
  const float* pos = (const float*)d_in[0];
  const float* box = (const float*)d_in[1];
  const int* shifts = (const int*)d_in[2];
  const float* cutp = (const float*)d_in[3];
  int N = in_sizes[0] / 3;
  int S = in_sizes[2] / 3;
  long M = (long)out_size / 6;
  float* out = (float*)d_out;

  int* count = (int*)d_ws;

  long n4 = (long)out_size / 4;
  int NWB = (2 * N + 3) / 4;
  int NFB = (int)((n4 + (256L * FILL_ITERS) - 1) / (256L * FILL_ITERS));

  hipLaunchKernelGGL(k_count, dim3(N), dim3(256), 0, stream,
                     pos, box, shifts, cutp, N, S, count);
  hipLaunchKernelGGL(k_main, dim3(NWB + NFB), dim3(256), 0, stream,
                     pos, box, shifts, cutp, N, S, count, out, M, n4, NWB);
}